// Round 10
// baseline (551.318 us; speedup 1.0000x reference)
//
#include <hip/hip_runtime.h>
#include <math.h>

typedef float f32x4 __attribute__((ext_vector_type(4)));

// ---------------------------------------------------------------------------
// Kernel 1: sinusoidal embed + Linear/SiLU x2 -> h2 into workspace (4 MB).
// 512 blocks x 256 threads, 16 batches/block, 2 blocks/CU (80 KB LDS).
// R9-style weight staging: coalesced float4 global reads, LDS transposed +
// XOR-swizzled  WL[k*128 + (j^(k&31))] = W[j][k]:
//   - staging writes: 4-way bank conflict (x1.58, only 128 instr/thread)
//   - compute reads (lane jj consecutive): 2 lanes/bank -> free
// Each thread keeps 8 batch-accumulators -> one weight read feeds 32 FMAs.
// ---------------------------------------------------------------------------
__global__ __launch_bounds__(256) void k_mlp(
    const float* __restrict__ t,
    const float* __restrict__ W1, const float* __restrict__ b1,
    const float* __restrict__ W2, const float* __restrict__ b2,
    float* __restrict__ hs)
{
    __shared__ float WL[128 * 128];                               // 64 KB
    __shared__ __attribute__((aligned(16))) float emb[16][128];   // 8 KB
    __shared__ __attribute__((aligned(16))) float h1[16][128];    // 8 KB

    const int tid  = threadIdx.x;
    const int base = blockIdx.x * 16;
    const int jj   = tid & 127;   // neuron
    const int half = tid >> 7;    // wave-uniform: batches half*8 .. half*8+7

    // ---- stage W1 (coalesced read, transposed+swizzled LDS write) ----
    {
        const f32x4* g = (const f32x4*)W1;     // 4096 float4
        #pragma unroll
        for (int it = 0; it < 16; ++it) {
            int idx4 = it * 256 + tid;         // [0,4096)
            f32x4 q = g[idx4];
            int j  = idx4 >> 5;                // row in W
            int k0 = (idx4 & 31) * 4;          // col base
            #pragma unroll
            for (int i = 0; i < 4; ++i) {
                int k = k0 + i;
                WL[k * 128 + (j ^ (k & 31))] = q[i];
            }
        }
    }
    // ---- embedding: 16 batches x 64 freqs = 1024 items, 4/thread ----
    #pragma unroll
    for (int i = 0; i < 4; ++i) {
        int idx = i * 256 + tid;               // [0,1024)
        int b = idx >> 6, k = idx & 63;
        double a   = (double)k * (6.907755278982137 / 63.0);
        float freq = (float)exp(a);
        float ang  = 6.2831853071795865f * freq;
        float ph   = t[base + b] * ang;
        float sv, cv;
        sincosf(ph, &sv, &cv);
        emb[b][k]      = sv;
        emb[b][64 + k] = cv;
    }
    __syncthreads();

    // ---- layer 1: h1[b][jj] = silu(b1[jj] + sum_k emb[b][k]*W1[jj,k]) ----
    {
        float acc[8];
        float bv = b1[jj];
        #pragma unroll
        for (int m = 0; m < 8; ++m) acc[m] = bv;
        #pragma unroll
        for (int k4 = 0; k4 < 32; ++k4) {
            const int k0 = k4 * 4;
            float w0 = WL[(k0 + 0) * 128 + (jj ^ ((k0 + 0) & 31))];
            float w1 = WL[(k0 + 1) * 128 + (jj ^ ((k0 + 1) & 31))];
            float w2 = WL[(k0 + 2) * 128 + (jj ^ ((k0 + 2) & 31))];
            float w3 = WL[(k0 + 3) * 128 + (jj ^ ((k0 + 3) & 31))];
            #pragma unroll
            for (int m = 0; m < 8; ++m) {
                float4 ev = ((const float4*)emb[half * 8 + m])[k4]; // broadcast
                acc[m] = fmaf(w0, ev.x, acc[m]);
                acc[m] = fmaf(w1, ev.y, acc[m]);
                acc[m] = fmaf(w2, ev.z, acc[m]);
                acc[m] = fmaf(w3, ev.w, acc[m]);
            }
        }
        #pragma unroll
        for (int m = 0; m < 8; ++m) {
            float a = acc[m];
            h1[half * 8 + m][jj] = a / (1.0f + expf(-a));   // SiLU
        }
    }
    __syncthreads();

    // ---- restage W2 over WL ----
    {
        const f32x4* g = (const f32x4*)W2;
        #pragma unroll
        for (int it = 0; it < 16; ++it) {
            int idx4 = it * 256 + tid;
            f32x4 q = g[idx4];
            int j  = idx4 >> 5;
            int k0 = (idx4 & 31) * 4;
            #pragma unroll
            for (int i = 0; i < 4; ++i) {
                int k = k0 + i;
                WL[k * 128 + (j ^ (k & 31))] = q[i];
            }
        }
    }
    __syncthreads();

    // ---- layer 2 -> hs (coalesced) ----
    {
        float acc[8];
        float bv = b2[jj];
        #pragma unroll
        for (int m = 0; m < 8; ++m) acc[m] = bv;
        #pragma unroll
        for (int k4 = 0; k4 < 32; ++k4) {
            const int k0 = k4 * 4;
            float w0 = WL[(k0 + 0) * 128 + (jj ^ ((k0 + 0) & 31))];
            float w1 = WL[(k0 + 1) * 128 + (jj ^ ((k0 + 1) & 31))];
            float w2 = WL[(k0 + 2) * 128 + (jj ^ ((k0 + 2) & 31))];
            float w3 = WL[(k0 + 3) * 128 + (jj ^ ((k0 + 3) & 31))];
            #pragma unroll
            for (int m = 0; m < 8; ++m) {
                float4 ev = ((const float4*)h1[half * 8 + m])[k4];  // broadcast
                acc[m] = fmaf(w0, ev.x, acc[m]);
                acc[m] = fmaf(w1, ev.y, acc[m]);
                acc[m] = fmaf(w2, ev.z, acc[m]);
                acc[m] = fmaf(w3, ev.w, acc[m]);
            }
        }
        #pragma unroll
        for (int m = 0; m < 8; ++m) {
            float a = acc[m];
            hs[(size_t)(base + half * 8 + m) * 128 + jj] = a / (1.0f + expf(-a));
        }
    }
}

// ---------------------------------------------------------------------------
// Kernel 2: pure broadcast store (proven R7/R8 shape, ~88 us = near the
// 6.3 TB/s fill stream). 1 tile (batch) per block, 8192 blocks.
// out[b,0,i,j] = h2[b,j].
// ---------------------------------------------------------------------------
__global__ __launch_bounds__(256) void k_bcast(
    const float* __restrict__ hs, float* __restrict__ out)
{
    const int tid = threadIdx.x;
    const size_t b = blockIdx.x;
    f32x4 v = ((const f32x4*)(hs + b * 128))[tid & 31];
    f32x4* d = (f32x4*)(out + b * 16384);
    #pragma unroll
    for (int c = 0; c < 16; ++c) {
        d[c * 256 + tid] = v;
    }
}

extern "C" void kernel_launch(void* const* d_in, const int* in_sizes, int n_in,
                              void* d_out, int out_size, void* d_ws, size_t ws_size,
                              hipStream_t stream) {
    const float* t  = (const float*)d_in[0];
    const float* W1 = (const float*)d_in[1];
    const float* b1 = (const float*)d_in[2];
    const float* W2 = (const float*)d_in[3];
    const float* b2 = (const float*)d_in[4];
    float* out = (float*)d_out;
    float* hs  = (float*)d_ws;          // 8192*128 f32 = 4 MB scratch
    const int B = in_sizes[0];          // 8192

    k_mlp  <<<B / 16, 256, 0, stream>>>(t, W1, b1, W2, b2, hs);
    k_bcast<<<B,      256, 0, stream>>>(hs, out);
}

// Round 11
// 536.427 us; speedup vs baseline: 1.0278x; 1.0278x over previous
//
#include <hip/hip_runtime.h>
#include <math.h>

typedef float f32x4 __attribute__((ext_vector_type(4)));

// ---------------------------------------------------------------------------
// Fully fused: sinusoidal embed + Linear/SiLU x2 + broadcast store.
// FP32 in / FP32 out. 512 blocks x 256 threads, 16 batches/block.
//
// LDS = exactly 80 KB -> 2 blocks/CU, one cohort round:
//   WQ[4096] float4 (64 KB): W staged as WQ[r*32 + (k4 ^ (r&31))] = W[r][4k4..]
//     - global reads: coalesced float4
//     - staging writes + compute reads: ds_*_b128 at stride-1-equivalent
//       bank spread (8 lanes/bank-quad, conflict-free)
//   EH (8 KB): embedding during layer 1, ALIASED by h2 after layer 2
//   H1 (8 KB): layer-1 activations
// Thread tile: 2 neurons (r0=tid&63, r0+64) x 4 batches (g=tid>>6) ->
// 8 accumulators; one b128 weight read feeds 16 FMAs; activation reads are
// wave-uniform LDS broadcasts. Store tail = proven R6/R9 pattern:
// out[b,0,i,j] = h2[b,j].
// ---------------------------------------------------------------------------
__global__ __launch_bounds__(256) void k_fused(
    const float* __restrict__ t,
    const float* __restrict__ W1, const float* __restrict__ b1,
    const float* __restrict__ W2, const float* __restrict__ b2,
    float* __restrict__ out)
{
    __shared__ __attribute__((aligned(16))) float4 WQ[4096];     // 64 KB
    __shared__ __attribute__((aligned(16))) float  EH[16 * 128]; // 8 KB: emb -> h2
    __shared__ __attribute__((aligned(16))) float  H1[16 * 128]; // 8 KB

    const int tid  = threadIdx.x;
    const int base = blockIdx.x * 16;

    const int r0 = tid & 63;      // neuron pair: r0 and r0+64
    const int r1 = r0 + 64;
    const int g  = tid >> 6;      // batch quad: batches 4g..4g+3
    const int xr = tid & 31;      // xor key (r0&31 == r1&31)

    // ---- stage W1 ----
    {
        const float4* gp = (const float4*)W1;   // 4096 float4
        #pragma unroll
        for (int it = 0; it < 16; ++it) {
            int idx4 = it * 256 + tid;
            float4 q = gp[idx4];
            int r = idx4 >> 5, c = idx4 & 31;
            WQ[r * 32 + (c ^ (r & 31))] = q;
        }
    }
    // ---- embedding: 16 batches x 64 freqs = 1024 items, 4/thread ----
    #pragma unroll
    for (int i = 0; i < 4; ++i) {
        int idx = i * 256 + tid;
        int b = idx >> 6, k = idx & 63;
        double a   = (double)k * (6.907755278982137 / 63.0);
        float freq = (float)exp(a);
        float ang  = 6.2831853071795865f * freq;
        float ph   = t[base + b] * ang;
        float sv, cv;
        sincosf(ph, &sv, &cv);
        EH[b * 128 + k]      = sv;
        EH[b * 128 + 64 + k] = cv;
    }
    __syncthreads();

    // ---- layer 1: H1[b][r] = silu(b1[r] + sum_k emb[b][k]*W1[r,k]) ----
    {
        float acc0[4], acc1[4];
        float bv0 = b1[r0], bv1 = b1[r1];
        #pragma unroll
        for (int m = 0; m < 4; ++m) { acc0[m] = bv0; acc1[m] = bv1; }
        #pragma unroll
        for (int k4 = 0; k4 < 32; ++k4) {
            float4 w0 = WQ[r0 * 32 + (k4 ^ xr)];
            float4 w1 = WQ[r1 * 32 + (k4 ^ xr)];
            #pragma unroll
            for (int m = 0; m < 4; ++m) {
                float4 ev = ((const float4*)(EH + (g * 4 + m) * 128))[k4]; // broadcast
                acc0[m] = fmaf(w0.x, ev.x, acc0[m]);
                acc0[m] = fmaf(w0.y, ev.y, acc0[m]);
                acc0[m] = fmaf(w0.z, ev.z, acc0[m]);
                acc0[m] = fmaf(w0.w, ev.w, acc0[m]);
                acc1[m] = fmaf(w1.x, ev.x, acc1[m]);
                acc1[m] = fmaf(w1.y, ev.y, acc1[m]);
                acc1[m] = fmaf(w1.z, ev.z, acc1[m]);
                acc1[m] = fmaf(w1.w, ev.w, acc1[m]);
            }
        }
        #pragma unroll
        for (int m = 0; m < 4; ++m) {
            float a0 = acc0[m], a1 = acc1[m];
            H1[(g * 4 + m) * 128 + r0] = a0 / (1.0f + expf(-a0));   // SiLU
            H1[(g * 4 + m) * 128 + r1] = a1 / (1.0f + expf(-a1));
        }
    }
    __syncthreads();   // fences H1 writes + layer-1 WQ reads

    // ---- restage W2 over WQ ----
    {
        const float4* gp = (const float4*)W2;
        #pragma unroll
        for (int it = 0; it < 16; ++it) {
            int idx4 = it * 256 + tid;
            float4 q = gp[idx4];
            int r = idx4 >> 5, c = idx4 & 31;
            WQ[r * 32 + (c ^ (r & 31))] = q;
        }
    }
    __syncthreads();

    // ---- layer 2: EH[b][r] = silu(b2[r] + sum_k H1[b][k]*W2[r,k]) ----
    // (EH's embedding contents are dead after layer 1 -> safe to overwrite.)
    {
        float acc0[4], acc1[4];
        float bv0 = b2[r0], bv1 = b2[r1];
        #pragma unroll
        for (int m = 0; m < 4; ++m) { acc0[m] = bv0; acc1[m] = bv1; }
        #pragma unroll
        for (int k4 = 0; k4 < 32; ++k4) {
            float4 w0 = WQ[r0 * 32 + (k4 ^ xr)];
            float4 w1 = WQ[r1 * 32 + (k4 ^ xr)];
            #pragma unroll
            for (int m = 0; m < 4; ++m) {
                float4 ev = ((const float4*)(H1 + (g * 4 + m) * 128))[k4]; // broadcast
                acc0[m] = fmaf(w0.x, ev.x, acc0[m]);
                acc0[m] = fmaf(w0.y, ev.y, acc0[m]);
                acc0[m] = fmaf(w0.z, ev.z, acc0[m]);
                acc0[m] = fmaf(w0.w, ev.w, acc0[m]);
                acc1[m] = fmaf(w1.x, ev.x, acc1[m]);
                acc1[m] = fmaf(w1.y, ev.y, acc1[m]);
                acc1[m] = fmaf(w1.z, ev.z, acc1[m]);
                acc1[m] = fmaf(w1.w, ev.w, acc1[m]);
            }
        }
        #pragma unroll
        for (int m = 0; m < 4; ++m) {
            float a0 = acc0[m], a1 = acc1[m];
            EH[(g * 4 + m) * 128 + r0] = a0 / (1.0f + expf(-a0));   // SiLU
            EH[(g * 4 + m) * 128 + r1] = a1 / (1.0f + expf(-a1));
        }
    }
    __syncthreads();

    // ---- broadcast store (proven pattern): tile = 4096 float4 chunks;
    // thread writes chunks c*256+tid; in-row chunk = tid&31 -> v invariant.
    #pragma unroll
    for (int m = 0; m < 16; ++m) {
        f32x4 v = *(const f32x4*)&EH[m * 128 + (tid & 31) * 4];
        f32x4* d = (f32x4*)(out + (size_t)(base + m) * 16384);
        #pragma unroll
        for (int c = 0; c < 16; ++c) {
            d[c * 256 + tid] = v;
        }
    }
}

extern "C" void kernel_launch(void* const* d_in, const int* in_sizes, int n_in,
                              void* d_out, int out_size, void* d_ws, size_t ws_size,
                              hipStream_t stream) {
    const float* t  = (const float*)d_in[0];
    const float* W1 = (const float*)d_in[1];
    const float* b1 = (const float*)d_in[2];
    const float* W2 = (const float*)d_in[3];
    const float* b2 = (const float*)d_in[4];
    float* out = (float*)d_out;
    const int B = in_sizes[0];   // 8192

    k_fused<<<B / 16, 256, 0, stream>>>(t, W1, b1, W2, b2, out);
}

// Round 12
// 536.130 us; speedup vs baseline: 1.0283x; 1.0006x over previous
//
#include <hip/hip_runtime.h>
#include <math.h>

typedef float f32x4 __attribute__((ext_vector_type(4)));

// ---------------------------------------------------------------------------
// Fully fused: sinusoidal embed + Linear/SiLU x2 + broadcast store.
// FP32 in / FP32 out. 1024 blocks x 256 threads, 8 batches/block.
//
// 72 KB LDS -> 2 blocks/CU, TWO cohort rounds: cohort-2's compute overlaps
// cohort-1's store stream (R11 was one cohort = compute fully serialized
// with stores; R9 was two cohorts but with ~2x costlier per-block compute).
//
//   WQ[4096] float4 (64 KB): W staged as WQ[r*32 + (k4 ^ (r&31))] = W[r][4k4..]
//     - global reads coalesced float4; LDS staging writes / compute reads are
//       ds_*_b128, conflict-free (2 lanes/bank worst case, R11-proven layout)
//   EH (4 KB): embedding during layer 1, aliased by h2 after layer 2
//   H1 (4 KB): layer-1 activations
//
// Thread tile: 1 neuron (r = tid&127) x 4 batches (g = tid>>7) -> 4 acc;
// one b128 weight read feeds 16 FMAs; activation reads are wave-uniform LDS
// broadcasts. Per-neuron math order identical to R11 -> bitwise-same output.
// Store tail = proven pattern: out[b,0,i,j] = h2[b,j].
// ---------------------------------------------------------------------------
__global__ __launch_bounds__(256) void k_fused(
    const float* __restrict__ t,
    const float* __restrict__ W1, const float* __restrict__ b1,
    const float* __restrict__ W2, const float* __restrict__ b2,
    float* __restrict__ out)
{
    __shared__ __attribute__((aligned(16))) float4 WQ[4096];    // 64 KB
    __shared__ __attribute__((aligned(16))) float  EH[8 * 128]; // 4 KB: emb -> h2
    __shared__ __attribute__((aligned(16))) float  H1[8 * 128]; // 4 KB

    const int tid  = threadIdx.x;
    const int base = blockIdx.x * 8;

    const int r  = tid & 127;     // neuron
    const int g  = tid >> 7;      // wave-uniform: batches 4g..4g+3
    const int xr = r & 31;        // xor key

    // ---- stage W1 (coalesced read, swizzled conflict-free b128 write) ----
    {
        const float4* gp = (const float4*)W1;   // 4096 float4
        #pragma unroll
        for (int it = 0; it < 16; ++it) {
            int idx4 = it * 256 + tid;
            float4 q = gp[idx4];
            int rr = idx4 >> 5, c = idx4 & 31;
            WQ[rr * 32 + (c ^ (rr & 31))] = q;
        }
    }
    // ---- embedding: 8 batches x 64 freqs = 512 items, 2/thread ----
    #pragma unroll
    for (int i = 0; i < 2; ++i) {
        int idx = i * 256 + tid;
        int b = idx >> 6, k = idx & 63;
        double a   = (double)k * (6.907755278982137 / 63.0);
        float freq = (float)exp(a);
        float ang  = 6.2831853071795865f * freq;
        float ph   = t[base + b] * ang;
        float sv, cv;
        sincosf(ph, &sv, &cv);
        EH[b * 128 + k]      = sv;
        EH[b * 128 + 64 + k] = cv;
    }
    __syncthreads();

    // ---- layer 1: H1[b][r] = silu(b1[r] + sum_k emb[b][k]*W1[r,k]) ----
    {
        float acc[4];
        float bv = b1[r];
        #pragma unroll
        for (int m = 0; m < 4; ++m) acc[m] = bv;
        #pragma unroll
        for (int k4 = 0; k4 < 32; ++k4) {
            float4 w = WQ[r * 32 + (k4 ^ xr)];
            #pragma unroll
            for (int m = 0; m < 4; ++m) {
                float4 ev = ((const float4*)(EH + (g * 4 + m) * 128))[k4]; // broadcast
                acc[m] = fmaf(w.x, ev.x, acc[m]);
                acc[m] = fmaf(w.y, ev.y, acc[m]);
                acc[m] = fmaf(w.z, ev.z, acc[m]);
                acc[m] = fmaf(w.w, ev.w, acc[m]);
            }
        }
        #pragma unroll
        for (int m = 0; m < 4; ++m) {
            float a = acc[m];
            H1[(g * 4 + m) * 128 + r] = a / (1.0f + expf(-a));   // SiLU
        }
    }
    __syncthreads();   // fences H1 writes + layer-1 WQ reads

    // ---- restage W2 over WQ ----
    {
        const float4* gp = (const float4*)W2;
        #pragma unroll
        for (int it = 0; it < 16; ++it) {
            int idx4 = it * 256 + tid;
            float4 q = gp[idx4];
            int rr = idx4 >> 5, c = idx4 & 31;
            WQ[rr * 32 + (c ^ (rr & 31))] = q;
        }
    }
    __syncthreads();

    // ---- layer 2: EH[b][r] = silu(b2[r] + sum_k H1[b][k]*W2[r,k]) ----
    // (EH's embedding contents are dead after layer 1 -> safe to overwrite.)
    {
        float acc[4];
        float bv = b2[r];
        #pragma unroll
        for (int m = 0; m < 4; ++m) acc[m] = bv;
        #pragma unroll
        for (int k4 = 0; k4 < 32; ++k4) {
            float4 w = WQ[r * 32 + (k4 ^ xr)];
            #pragma unroll
            for (int m = 0; m < 4; ++m) {
                float4 ev = ((const float4*)(H1 + (g * 4 + m) * 128))[k4]; // broadcast
                acc[m] = fmaf(w.x, ev.x, acc[m]);
                acc[m] = fmaf(w.y, ev.y, acc[m]);
                acc[m] = fmaf(w.z, ev.z, acc[m]);
                acc[m] = fmaf(w.w, ev.w, acc[m]);
            }
        }
        #pragma unroll
        for (int m = 0; m < 4; ++m) {
            float a = acc[m];
            EH[(g * 4 + m) * 128 + r] = a / (1.0f + expf(-a));   // SiLU
        }
    }
    __syncthreads();

    // ---- broadcast store (proven pattern): tile = 4096 float4 chunks;
    // thread writes chunks c*256+tid; in-row chunk = tid&31 -> v invariant.
    #pragma unroll
    for (int m = 0; m < 8; ++m) {
        f32x4 v = *(const f32x4*)&EH[m * 128 + (tid & 31) * 4];
        f32x4* d = (f32x4*)(out + (size_t)(base + m) * 16384);
        #pragma unroll
        for (int c = 0; c < 16; ++c) {
            d[c * 256 + tid] = v;
        }
    }
}

extern "C" void kernel_launch(void* const* d_in, const int* in_sizes, int n_in,
                              void* d_out, int out_size, void* d_ws, size_t ws_size,
                              hipStream_t stream) {
    const float* t  = (const float*)d_in[0];
    const float* W1 = (const float*)d_in[1];
    const float* b1 = (const float*)d_in[2];
    const float* W2 = (const float*)d_in[3];
    const float* b2 = (const float*)d_in[4];
    float* out = (float*)d_out;
    const int B = in_sizes[0];   // 8192

    k_fused<<<B / 8, 256, 0, stream>>>(t, W1, b1, W2, b2, out);
}